// Round 1
// baseline (1746.758 us; speedup 1.0000x reference)
//
#include <hip/hip_runtime.h>
#include <math.h>

#define NPTS 16384
#define KNB 20

// ---------------- workspace layout (bytes, all naturally 256-aligned) ----------------
static const size_t OFF_F0   = 0;                                   // N x float4
static const size_t OFF_SSQ0 = OFF_F0   + (size_t)NPTS*4*4;         // N f32
static const size_t OFF_IDX1 = OFF_SSQ0 + (size_t)NPTS*4;           // N*20 i32
static const size_t OFF_XMX1 = OFF_IDX1 + (size_t)NPTS*KNB*4;       // N*64 f32
static const size_t OFF_XMN1 = OFF_XMX1 + (size_t)NPTS*64*4;        // N*64 f32
static const size_t OFF_SUM1 = OFF_XMN1 + (size_t)NPTS*64*4;        // 128 f32 (sum,sumsq)
static const size_t OFF_X1   = OFF_SUM1 + 512;                      // N*64 f32
static const size_t OFF_SSQ1 = OFF_X1   + (size_t)NPTS*64*4;        // N f32
static const size_t OFF_IDX2 = OFF_SSQ1 + (size_t)NPTS*4;           // N*20 i32 (global idx)
static const size_t OFF_XMX2 = OFF_IDX2 + (size_t)NPTS*KNB*4;       // N*128 f32
static const size_t OFF_XMN2 = OFF_XMX2 + (size_t)NPTS*128*4;       // N*128 f32
static const size_t OFF_SUM2 = OFF_XMN2 + (size_t)NPTS*128*4;       // 256 f32
static const size_t OFF_X2   = OFF_SUM2 + 1024;                     // N*128 f32
static const size_t OFF_SUMF = OFF_X2   + (size_t)NPTS*128*4;       // 512 f32
static const size_t OFF_HPMX = OFF_SUMF + 2048;                     // 8*256 u32 (float bits)
static const size_t OFF_HPMN = OFF_HPMX + 8*256*4;                  // 8*256 u32

// ---------------- helpers ----------------
__device__ __forceinline__ float dot4f(float4 a, float4 b) {
  return a.x*b.x + a.y*b.y + a.z*b.z + a.w*b.w;
}

// fixed-order 64-d dot: used for BOTH row norms and cross dots so that
// d(i,i) == (sq - 2*sq) + sq == 0 exactly (self always selected, like jax top_k)
__device__ __forceinline__ float dot64v(const float* a, const float4* b4) {
  float s = 0.f;
  #pragma unroll
  for (int d4 = 0; d4 < 16; ++d4) {
    float4 b = b4[d4];
    s += a[4*d4+0]*b.x + a[4*d4+1]*b.y + a[4*d4+2]*b.z + a[4*d4+3]*b.w;
  }
  return s;
}

// sorted top-K (ascending) insertion; all indices static after unroll -> stays in VGPRs
__device__ __forceinline__ void topk_insert(float (&bd)[KNB], int (&bi)[KNB], float d, int j) {
  if (d < bd[KNB-1]) {
    bd[KNB-1] = d; bi[KNB-1] = j;
    #pragma unroll
    for (int s = KNB-1; s > 0; --s) {
      if (bd[s] < bd[s-1]) {
        float td = bd[s]; bd[s] = bd[s-1]; bd[s-1] = td;
        int   ti = bi[s]; bi[s] = bi[s-1]; bi[s-1] = ti;
      }
    }
  }
}

// ---------------- init (atomic accumulators must be reset EVERY launch) ----------------
__global__ void k_init(float* sum1, float* sum2, float* sumF, unsigned* hpmx, unsigned* hpmn) {
  int t = blockIdx.x*256 + threadIdx.x;
  if (t < 128) sum1[t] = 0.f;
  if (t < 256) sum2[t] = 0.f;
  if (t < 512) sumF[t] = 0.f;
  if (t < 2048) { hpmx[t] = 0u; hpmn[t] = 0x7f800000u; }   // relu>=0 -> uint order == float order
}

// ---------------- f0 = [pos,x], ssq0 ----------------
__global__ __launch_bounds__(256) void k_f0(const float* __restrict__ pos, const float* __restrict__ x,
                                            float4* __restrict__ f0, float* __restrict__ ssq) {
  int i = blockIdx.x*256 + threadIdx.x;
  if (i >= NPTS) return;
  float4 f;
  f.x = pos[3*i+0]; f.y = pos[3*i+1]; f.z = pos[3*i+2]; f.w = x[i];
  f0[i] = f;
  ssq[i] = dot4f(f, f);
}

// ---------------- knn1: global 16384-point knn in 4-d ----------------
// 4 threads per row (column quarters), 64 rows/block, LDS column tiles of 2048
__global__ __launch_bounds__(256) void k_knn1(const float4* __restrict__ f0, const float* __restrict__ ssq,
                                              int* __restrict__ idx1) {
  __shared__ __align__(16) float4 tf[2048];
  __shared__ float tq[2048];
  int t = threadIdx.x;
  int row = blockIdx.x*64 + (t>>2);
  int q = t & 3;
  float4 fi = f0[row];
  float sqi = ssq[row];
  float bd[KNB]; int bi[KNB];
  #pragma unroll
  for (int s = 0; s < KNB; ++s) { bd[s] = INFINITY; bi[s] = 0; }
  for (int tile = 0; tile < NPTS/2048; ++tile) {
    int base = tile*2048;
    __syncthreads();
    for (int v = t; v < 2048; v += 256) { tf[v] = f0[base+v]; tq[v] = ssq[base+v]; }
    __syncthreads();
    for (int jj = 0; jj < 512; ++jj) {
      int jl = jj*4 + q;                              // quarters interleaved -> conflict-free
      float d = (sqi - 2.f*dot4f(fi, tf[jl])) + tq[jl];
      topk_insert(bd, bi, d, base + jl);
    }
  }
  // merge the 4 quarters (snapshot partner list, then insert)
  {
    float pd[KNB]; int pi[KNB];
    #pragma unroll
    for (int s=0;s<KNB;s++){ pd[s]=__shfl_xor(bd[s],1); pi[s]=__shfl_xor(bi[s],1); }
    #pragma unroll
    for (int s=0;s<KNB;s++) topk_insert(bd, bi, pd[s], pi[s]);
    #pragma unroll
    for (int s=0;s<KNB;s++){ pd[s]=__shfl_xor(bd[s],2); pi[s]=__shfl_xor(bi[s],2); }
    #pragma unroll
    for (int s=0;s<KNB;s++) topk_insert(bd, bi, pd[s], pi[s]);
  }
  if (q == 0) {
    #pragma unroll
    for (int s=0;s<KNB;s++) idx1[row*KNB+s] = bi[s];
  }
}

// ---------------- mlp1: edge MLP 8->64, relu, per-point max/min (pre-BN), channel sums ----------------
// wave per point: lane = channel
__global__ __launch_bounds__(256) void k_mlp1(const float4* __restrict__ f0, const int* __restrict__ idx1,
                                              const float* __restrict__ w1, const float* __restrict__ b1,
                                              float* __restrict__ xmx, float* __restrict__ xmn,
                                              float* __restrict__ sums) {
  __shared__ float rs[256], rs2[256];
  int t = threadIdx.x;
  int c = t & 63;
  int w = t >> 6;
  float wc[8];
  #pragma unroll
  for (int d = 0; d < 8; ++d) wc[d] = w1[d*64 + c];
  float bc = b1[c];
  float s = 0.f, s2 = 0.f;
  for (int p = 0; p < 8; ++p) {
    int i = blockIdx.x*32 + p*4 + w;
    float4 fi = f0[i];
    float mx = -INFINITY, mn = INFINITY;
    #pragma unroll
    for (int k = 0; k < KNB; ++k) {
      int j = idx1[i*KNB + k];
      float4 fj = f0[j];
      float h = bc + fi.x*wc[0] + fi.y*wc[1] + fi.z*wc[2] + fi.w*wc[3]
                   + (fj.x-fi.x)*wc[4] + (fj.y-fi.y)*wc[5] + (fj.z-fi.z)*wc[6] + (fj.w-fi.w)*wc[7];
      h = fmaxf(h, 0.f);
      mx = fmaxf(mx, h); mn = fminf(mn, h);
      s += h; s2 += h*h;
    }
    xmx[i*64+c] = mx; xmn[i*64+c] = mn;
  }
  rs[t] = s; rs2[t] = s2;
  __syncthreads();
  if (t < 64) {
    atomicAdd(&sums[c],      rs[t]+rs[t+64]+rs[t+128]+rs[t+192]);
    atomicAdd(&sums[64+c],   rs2[t]+rs2[t+64]+rs2[t+128]+rs2[t+192]);
  }
}

// ---------------- bn1 apply: x1 = affine(max or min by scale sign) ----------------
__global__ __launch_bounds__(256) void k_bn1apply(const float* __restrict__ sums, const float* __restrict__ g,
                                                  const float* __restrict__ be, const float* __restrict__ xmx,
                                                  const float* __restrict__ xmn, float* __restrict__ x1) {
  __shared__ float sc_s[64], sh_s[64];
  int t = threadIdx.x;
  if (t < 64) {
    float m = sums[t] * (1.f/327680.f);
    float v = sums[64+t] * (1.f/327680.f) - m*m;
    float sc = g[t] / sqrtf(v + 1e-5f);
    sc_s[t] = sc; sh_s[t] = be[t] - m*sc;
  }
  __syncthreads();
  int c = t & 63;
  int i = blockIdx.x*4 + (t>>6);
  float sc = sc_s[c], sh = sh_s[c];
  float val = (sc >= 0.f) ? xmx[i*64+c] : xmn[i*64+c];
  x1[i*64+c] = sc*val + sh;
}

// ---------------- ssq1 (same dot64v ordering as knn2 for exact self-distance) ----------------
__global__ __launch_bounds__(256) void k_ssq1(const float* __restrict__ x1, float* __restrict__ ssq1) {
  int i = blockIdx.x*256 + threadIdx.x;
  alignas(16) float f[64];
  #pragma unroll
  for (int d4 = 0; d4 < 16; ++d4) ((float4*)f)[d4] = ((const float4*)x1)[i*16 + d4];
  ssq1[i] = dot64v(f, (const float4*)f);
}

// ---------------- knn2: per-batch knn over 2048 points in 64-d ----------------
__global__ __launch_bounds__(256) void k_knn2(const float* __restrict__ x1, const float* __restrict__ ssq1,
                                              int* __restrict__ idx2) {
  __shared__ __align__(16) float tf[128][68];   // pad 68 -> conflict-free 4-row float4 reads
  __shared__ float tq[128];
  int t = threadIdx.x;
  int row = blockIdx.x*64 + (t>>2);
  int q = t & 3;
  int cbase = (row >> 11) << 11;                // batch column base
  alignas(16) float fi[64];
  #pragma unroll
  for (int d4 = 0; d4 < 16; ++d4) ((float4*)fi)[d4] = ((const float4*)x1)[row*16 + d4];
  float sqi = ssq1[row];
  float bd[KNB]; int bi[KNB];
  #pragma unroll
  for (int s = 0; s < KNB; ++s) { bd[s] = INFINITY; bi[s] = 0; }
  for (int tile = 0; tile < 16; ++tile) {
    int base = cbase + tile*128;
    __syncthreads();
    for (int v = t; v < 128*16; v += 256) {
      int jl = v >> 4, d4 = v & 15;
      *(float4*)&tf[jl][d4*4] = ((const float4*)x1)[(base+jl)*16 + d4];
    }
    if (t < 128) tq[t] = ssq1[base + t];
    __syncthreads();
    for (int jj = 0; jj < 32; ++jj) {
      int jl = jj*4 + q;
      float d = (sqi - 2.f*dot64v(fi, (const float4*)&tf[jl][0])) + tq[jl];
      topk_insert(bd, bi, d, base + jl);        // GLOBAL index stored
    }
  }
  {
    float pd[KNB]; int pi[KNB];
    #pragma unroll
    for (int s=0;s<KNB;s++){ pd[s]=__shfl_xor(bd[s],1); pi[s]=__shfl_xor(bi[s],1); }
    #pragma unroll
    for (int s=0;s<KNB;s++) topk_insert(bd, bi, pd[s], pi[s]);
    #pragma unroll
    for (int s=0;s<KNB;s++){ pd[s]=__shfl_xor(bd[s],2); pi[s]=__shfl_xor(bi[s],2); }
    #pragma unroll
    for (int s=0;s<KNB;s++) topk_insert(bd, bi, pd[s], pi[s]);
  }
  if (q == 0) {
    #pragma unroll
    for (int s=0;s<KNB;s++) idx2[row*KNB+s] = bi[s];
  }
}

// ---------------- mlp2: edge MLP 128->128, relu, per-point max/min, channel sums ----------------
// w2 staged in LDS (64KB); per point stage 20x128 edge matrix; 256 thr = 128ch x 2 edge-halves
__global__ __launch_bounds__(256) void k_mlp2(const float* __restrict__ x1, const int* __restrict__ idx2,
                                              const float* __restrict__ w2, const float* __restrict__ b2,
                                              float* __restrict__ xmx, float* __restrict__ xmn,
                                              float* __restrict__ sums) {
  __shared__ __align__(16) float w2s[128*128];
  __shared__ __align__(16) float es[KNB*128];
  __shared__ float red[256];
  __shared__ int js[KNB];
  int t = threadIdx.x;
  for (int v = t; v < 128*32; v += 256) ((float4*)w2s)[v] = ((const float4*)w2)[v];
  int c = t & 127, half = t >> 7;
  float bc = b2[c];
  float s = 0.f, s2 = 0.f;
  for (int p = 0; p < 32; ++p) {
    int i = blockIdx.x*32 + p;
    __syncthreads();                              // protects es/red reuse; first iter: w2s ready after next sync
    if (t < KNB) js[t] = idx2[i*KNB + t];
    __syncthreads();
    for (int v = t; v < KNB*32; v += 256) {       // 640 float4 = 20 edges x 32
      int k = v >> 5, d4 = v & 31;
      int j = js[k];
      float4 e;
      if (d4 < 16) {
        e = ((const float4*)x1)[i*16 + d4];
      } else {
        float4 a  = ((const float4*)x1)[j*16 + (d4-16)];
        float4 xi = ((const float4*)x1)[i*16 + (d4-16)];
        e = make_float4(a.x-xi.x, a.y-xi.y, a.z-xi.z, a.w-xi.w);
      }
      ((float4*)es)[v] = e;
    }
    __syncthreads();
    float acc[10];
    #pragma unroll
    for (int k = 0; k < 10; ++k) acc[k] = 0.f;
    int kbase = half*10;
    for (int d4 = 0; d4 < 32; ++d4) {
      float w0 = w2s[(d4*4+0)*128 + c];
      float w1v = w2s[(d4*4+1)*128 + c];
      float w2v = w2s[(d4*4+2)*128 + c];
      float w3 = w2s[(d4*4+3)*128 + c];
      #pragma unroll
      for (int k = 0; k < 10; ++k) {
        float4 e = ((const float4*)es)[(kbase+k)*32 + d4];   // wave-uniform addr -> broadcast
        acc[k] += e.x*w0 + e.y*w1v + e.z*w2v + e.w*w3;
      }
    }
    float mx = -INFINITY, mn = INFINITY;
    #pragma unroll
    for (int k = 0; k < 10; ++k) {
      float h = fmaxf(acc[k] + bc, 0.f);
      mx = fmaxf(mx, h); mn = fminf(mn, h);
      s += h; s2 += h*h;
    }
    red[t] = mx; __syncthreads();
    float omx = fmaxf(mx, red[c+128]);
    __syncthreads();
    red[t] = mn; __syncthreads();
    if (half == 0) {
      xmx[i*128+c] = omx;
      xmn[i*128+c] = fminf(mn, red[c+128]);
    }
  }
  __syncthreads();
  red[t] = s; __syncthreads();
  if (half == 0) atomicAdd(&sums[c], s + red[c+128]);
  __syncthreads();
  red[t] = s2; __syncthreads();
  if (half == 0) atomicAdd(&sums[128+c], s2 + red[c+128]);
}

// ---------------- bn2 apply ----------------
__global__ __launch_bounds__(256) void k_bn2apply(const float* __restrict__ sums, const float* __restrict__ g,
                                                  const float* __restrict__ be, const float* __restrict__ xmx,
                                                  const float* __restrict__ xmn, float* __restrict__ x2) {
  __shared__ float sc_s[128], sh_s[128];
  int t = threadIdx.x;
  if (t < 128) {
    float m = sums[t] * (1.f/327680.f);
    float v = sums[128+t] * (1.f/327680.f) - m*m;
    float sc = g[t] / sqrtf(v + 1e-5f);
    sc_s[t] = sc; sh_s[t] = be[t] - m*sc;
  }
  __syncthreads();
  int c = t & 127;
  int i = blockIdx.x*2 + (t>>7);
  float sc = sc_s[c], sh = sh_s[c];
  float val = (sc >= 0.f) ? xmx[i*128+c] : xmn[i*128+c];
  x2[i*128+c] = sc*val + sh;
}

// ---------------- gemmF: relu([x1|x2] @ wf + bf); channel sums + per-batch max/min only ----------------
// tiles: 64 rows x 64 cols, K=192 fully staged
__global__ __launch_bounds__(256) void k_gemmF(const float* __restrict__ x1, const float* __restrict__ x2,
                                               const float* __restrict__ wf, const float* __restrict__ bf,
                                               float* __restrict__ sumsF, unsigned* __restrict__ hpmx,
                                               unsigned* __restrict__ hpmn) {
  __shared__ float A_s[64*193];                  // pad 193 -> 2-way (free) reads
  __shared__ __align__(16) float B_s[192*64];
  __shared__ float red[1024];
  int t = threadIdx.x;
  int rt = blockIdx.x >> 2;
  int ct = blockIdx.x & 3;
  for (int v = t; v < 64*48; v += 256) {
    int r = v / 48, gg = v - r*48;
    int row = rt*64 + r;
    float4 e = (gg < 16) ? ((const float4*)x1)[row*16 + gg]
                         : ((const float4*)x2)[row*32 + (gg-16)];
    float* p = &A_s[r*193 + gg*4];
    p[0]=e.x; p[1]=e.y; p[2]=e.z; p[3]=e.w;
  }
  for (int v = t; v < 192*16; v += 256) {
    int d = v >> 4, c4 = v & 15;
    *(float4*)&B_s[d*64 + c4*4] = ((const float4*)wf)[d*64 + ct*16 + c4];
  }
  __syncthreads();
  int rg = t & 15, cg = t >> 4;
  float acc[4][4];
  #pragma unroll
  for (int a=0;a<4;a++) { acc[a][0]=0.f; acc[a][1]=0.f; acc[a][2]=0.f; acc[a][3]=0.f; }
  for (int d = 0; d < 192; ++d) {
    float a0 = A_s[(rg*4+0)*193 + d];
    float a1 = A_s[(rg*4+1)*193 + d];
    float a2 = A_s[(rg*4+2)*193 + d];
    float a3 = A_s[(rg*4+3)*193 + d];
    float b0 = B_s[d*64 + cg];
    float b1 = B_s[d*64 + cg + 16];
    float b2 = B_s[d*64 + cg + 32];
    float b3 = B_s[d*64 + cg + 48];
    acc[0][0]+=a0*b0; acc[0][1]+=a0*b1; acc[0][2]+=a0*b2; acc[0][3]+=a0*b3;
    acc[1][0]+=a1*b0; acc[1][1]+=a1*b1; acc[1][2]+=a1*b2; acc[1][3]+=a1*b3;
    acc[2][0]+=a2*b0; acc[2][1]+=a2*b1; acc[2][2]+=a2*b2; acc[2][3]+=a2*b3;
    acc[3][0]+=a3*b0; acc[3][1]+=a3*b1; acc[3][2]+=a3*b2; acc[3][3]+=a3*b3;
  }
  float hv[4][4];
  #pragma unroll
  for (int ss=0; ss<4; ++ss) {
    float bb = bf[ct*64 + cg + ss*16];
    #pragma unroll
    for (int rr=0; rr<4; ++rr) hv[rr][ss] = fmaxf(acc[rr][ss] + bb, 0.f);
  }
  int b = rt >> 5;
  // sum
  #pragma unroll
  for (int ss=0; ss<4; ++ss) red[rg*64 + cg + ss*16] = hv[0][ss]+hv[1][ss]+hv[2][ss]+hv[3][ss];
  __syncthreads();
  if (t < 64) {
    float v = 0.f;
    #pragma unroll
    for (int r=0;r<16;r++) v += red[r*64 + t];
    atomicAdd(&sumsF[ct*64 + t], v);
  }
  __syncthreads();
  // sumsq
  #pragma unroll
  for (int ss=0; ss<4; ++ss) red[rg*64 + cg + ss*16] =
      hv[0][ss]*hv[0][ss]+hv[1][ss]*hv[1][ss]+hv[2][ss]*hv[2][ss]+hv[3][ss]*hv[3][ss];
  __syncthreads();
  if (t < 64) {
    float v = 0.f;
    #pragma unroll
    for (int r=0;r<16;r++) v += red[r*64 + t];
    atomicAdd(&sumsF[256 + ct*64 + t], v);
  }
  __syncthreads();
  // max
  #pragma unroll
  for (int ss=0; ss<4; ++ss) red[rg*64 + cg + ss*16] =
      fmaxf(fmaxf(hv[0][ss],hv[1][ss]), fmaxf(hv[2][ss],hv[3][ss]));
  __syncthreads();
  if (t < 64) {
    float v = -INFINITY;
    #pragma unroll
    for (int r=0;r<16;r++) v = fmaxf(v, red[r*64 + t]);
    atomicMax(&hpmx[b*256 + ct*64 + t], __float_as_uint(v));
  }
  __syncthreads();
  // min
  #pragma unroll
  for (int ss=0; ss<4; ++ss) red[rg*64 + cg + ss*16] =
      fminf(fminf(hv[0][ss],hv[1][ss]), fminf(hv[2][ss],hv[3][ss]));
  __syncthreads();
  if (t < 64) {
    float v = INFINITY;
    #pragma unroll
    for (int r=0;r<16;r++) v = fminf(v, red[r*64 + t]);
    atomicMin(&hpmn[b*256 + ct*64 + t], __float_as_uint(v));
  }
}

// ---------------- head: BNf apply on pooled max/min, 3 small MLPs + BN(8), log_softmax ----------------
__global__ __launch_bounds__(256) void k_head(const float* __restrict__ sumsF, const float* __restrict__ gf,
                                              const float* __restrict__ bef,
                                              const unsigned* __restrict__ hpmx, const unsigned* __restrict__ hpmn,
                                              const float* __restrict__ wo1, const float* __restrict__ bo1,
                                              const float* __restrict__ go1, const float* __restrict__ beo1,
                                              const float* __restrict__ wo2, const float* __restrict__ bo2,
                                              const float* __restrict__ go2, const float* __restrict__ beo2,
                                              const float* __restrict__ wo3, const float* __restrict__ bo3,
                                              float* __restrict__ out) {
  __shared__ float hp[8][256];
  __shared__ float u1[8][128];
  __shared__ float u2[8][64];
  __shared__ float lg[8][16];
  int t = threadIdx.x;
  {
    float m = sumsF[t] * (1.f/16384.f);
    float v = sumsF[256+t] * (1.f/16384.f) - m*m;
    float sc = gf[t] / sqrtf(v + 1e-5f);
    float sh = bef[t] - m*sc;
    for (int b = 0; b < 8; ++b) {
      unsigned bits = (sc >= 0.f) ? hpmx[b*256+t] : hpmn[b*256+t];
      hp[b][t] = sc*__uint_as_float(bits) + sh;
    }
  }
  __syncthreads();
  for (int p = t; p < 1024; p += 256) {
    int b = p >> 7, c = p & 127;
    float z = bo1[c];
    for (int d = 0; d < 256; ++d) z += hp[b][d]*wo1[d*128+c];
    u1[b][c] = fmaxf(z, 0.f);
  }
  __syncthreads();
  if (t < 128) {
    float m = 0.f;
    for (int b=0;b<8;b++) m += u1[b][t];
    m *= 0.125f;
    float v = 0.f;
    for (int b=0;b<8;b++) { float dd = u1[b][t]-m; v += dd*dd; }
    v *= 0.125f;
    float sc = go1[t]/sqrtf(v+1e-5f), sh = beo1[t]-m*sc;
    for (int b=0;b<8;b++) u1[b][t] = sc*u1[b][t]+sh;
  }
  __syncthreads();
  for (int p = t; p < 512; p += 256) {
    int b = p >> 6, c = p & 63;
    float z = bo2[c];
    for (int d = 0; d < 128; ++d) z += u1[b][d]*wo2[d*64+c];
    u2[b][c] = fmaxf(z, 0.f);
  }
  __syncthreads();
  if (t < 64) {
    float m = 0.f;
    for (int b=0;b<8;b++) m += u2[b][t];
    m *= 0.125f;
    float v = 0.f;
    for (int b=0;b<8;b++) { float dd = u2[b][t]-m; v += dd*dd; }
    v *= 0.125f;
    float sc = go2[t]/sqrtf(v+1e-5f), sh = beo2[t]-m*sc;
    for (int b=0;b<8;b++) u2[b][t] = sc*u2[b][t]+sh;
  }
  __syncthreads();
  if (t < 128) {
    int b = t >> 4, c = t & 15;
    float z = bo3[c];
    for (int d = 0; d < 64; ++d) z += u2[b][d]*wo3[d*16+c];
    lg[b][c] = z;
  }
  __syncthreads();
  if (t < 8) {
    float m = -INFINITY;
    for (int j=0;j<16;j++) m = fmaxf(m, lg[t][j]);
    float s = 0.f;
    for (int j=0;j<16;j++) s += expf(lg[t][j]-m);
    float ls = logf(s);
    for (int j=0;j<16;j++) out[t*16+j] = (lg[t][j]-m) - ls;
  }
}

// ---------------- launch ----------------
extern "C" void kernel_launch(void* const* d_in, const int* in_sizes, int n_in,
                              void* d_out, int out_size, void* d_ws, size_t ws_size,
                              hipStream_t stream) {
  (void)in_sizes; (void)n_in; (void)out_size; (void)ws_size;
  const float* pos = (const float*)d_in[0];
  const float* x   = (const float*)d_in[1];
  const float* w1  = (const float*)d_in[3];
  const float* b1  = (const float*)d_in[4];
  const float* g1  = (const float*)d_in[5];
  const float* be1 = (const float*)d_in[6];
  const float* w2  = (const float*)d_in[7];
  const float* b2  = (const float*)d_in[8];
  const float* g2  = (const float*)d_in[9];
  const float* be2 = (const float*)d_in[10];
  const float* wf  = (const float*)d_in[11];
  const float* bf  = (const float*)d_in[12];
  const float* gf  = (const float*)d_in[13];
  const float* bef = (const float*)d_in[14];
  const float* wo1 = (const float*)d_in[15];
  const float* bo1 = (const float*)d_in[16];
  const float* go1 = (const float*)d_in[17];
  const float* beo1= (const float*)d_in[18];
  const float* wo2 = (const float*)d_in[19];
  const float* bo2 = (const float*)d_in[20];
  const float* go2 = (const float*)d_in[21];
  const float* beo2= (const float*)d_in[22];
  const float* wo3 = (const float*)d_in[23];
  const float* bo3 = (const float*)d_in[24];

  char* ws = (char*)d_ws;
  float4*   f0    = (float4*)  (ws + OFF_F0);
  float*    ssq0  = (float*)   (ws + OFF_SSQ0);
  int*      idx1  = (int*)     (ws + OFF_IDX1);
  float*    xmx1  = (float*)   (ws + OFF_XMX1);
  float*    xmn1  = (float*)   (ws + OFF_XMN1);
  float*    sum1  = (float*)   (ws + OFF_SUM1);
  float*    x1    = (float*)   (ws + OFF_X1);
  float*    ssq1  = (float*)   (ws + OFF_SSQ1);
  int*      idx2  = (int*)     (ws + OFF_IDX2);
  float*    xmx2  = (float*)   (ws + OFF_XMX2);
  float*    xmn2  = (float*)   (ws + OFF_XMN2);
  float*    sum2  = (float*)   (ws + OFF_SUM2);
  float*    x2    = (float*)   (ws + OFF_X2);
  float*    sumF  = (float*)   (ws + OFF_SUMF);
  unsigned* hpmx  = (unsigned*)(ws + OFF_HPMX);
  unsigned* hpmn  = (unsigned*)(ws + OFF_HPMN);

  k_init    <<<8,    256, 0, stream>>>(sum1, sum2, sumF, hpmx, hpmn);
  k_f0      <<<64,   256, 0, stream>>>(pos, x, f0, ssq0);
  k_knn1    <<<256,  256, 0, stream>>>(f0, ssq0, idx1);
  k_mlp1    <<<512,  256, 0, stream>>>(f0, idx1, w1, b1, xmx1, xmn1, sum1);
  k_bn1apply<<<4096, 256, 0, stream>>>(sum1, g1, be1, xmx1, xmn1, x1);
  k_ssq1    <<<64,   256, 0, stream>>>(x1, ssq1);
  k_knn2    <<<256,  256, 0, stream>>>(x1, ssq1, idx2);
  k_mlp2    <<<512,  256, 0, stream>>>(x1, idx2, w2, b2, xmx2, xmn2, sum2);
  k_bn2apply<<<8192, 256, 0, stream>>>(sum2, g2, be2, xmx2, xmn2, x2);
  k_gemmF   <<<1024, 256, 0, stream>>>(x1, x2, wf, bf, sumF, hpmx, hpmn);
  k_head    <<<1,    256, 0, stream>>>(sumF, gf, bef, hpmx, hpmn,
                                       wo1, bo1, go1, beo1, wo2, bo2, go2, beo2, wo3, bo3,
                                       (float*)d_out);
}